// Round 1
// 196.553 us; speedup vs baseline: 1.0807x; 1.0807x over previous
//
#include <hip/hip_runtime.h>

typedef _Float16 half4 __attribute__((ext_vector_type(4)));
typedef _Float16 half8 __attribute__((ext_vector_type(8)));
typedef float f32x4 __attribute__((ext_vector_type(4)));

#define NNODE 8192
#define NHID  256
#define RCAP  128
#define KCAP  64
#define GLS   72    // gemm lds row stride (fp16): 144B = 9 quads, conflict-free
#define SK    136   // medoid lds row stride (fp16): 272B = 17 quads, conflict-free

struct SmemGemm  { _Float16 sA[64][GLS]; _Float16 sB[64][GLS]; };
struct SmemDedup { int lc[2][RCAP]; float lw[2][RCAP]; unsigned char kp[2][RCAP];
                   int cw[2][2]; float rw[2][2]; };
struct SmemMedoid {
    // s_red is only live AFTER the last sh read in the epilogue (one extra
    // barrier inserted there) -> alias it into sh. 24.0KB -> 18.9KB, which
    // lifts the LDS occupancy cap from 6 to 8 blocks/CU (32 waves = 100%).
    union {
        _Float16 sh[64][SK];
        float s_red[4][288];
    };
    float s_a[64]; float s_sq[64]; float s_cpart[2][64]; float s_u[64];
    int s_cols[64]; float s_rsum;
};

// ---------------------------------------------------------------- GEMM tile body (fp16 A, fp16 BT)
__device__ __forceinline__ void gemm_body(
    char* smraw, const _Float16* __restrict__ Ahi, const _Float16* __restrict__ BT,
    _Float16* __restrict__ Chi, int K, int bm, int bn) {
    SmemGemm& sm = *(SmemGemm*)smraw;
    const int t = threadIdx.x;
    const int lane = t & 63, L15 = lane & 15, q = lane >> 4;
    const int w = t >> 6, wr = w >> 1, wc = w & 1;
    f32x4 acc[2][2];
#pragma unroll
    for (int a = 0; a < 2; ++a)
#pragma unroll
        for (int b2 = 0; b2 < 2; ++b2) acc[a][b2] = (f32x4){0.f, 0.f, 0.f, 0.f};

    for (int k0 = 0; k0 < K; k0 += 64) {
#pragma unroll
        for (int i = 0; i < 2; ++i) {
            int row = i * 32 + (t >> 3), ch = t & 7;
            *(half8*)&sm.sA[row][ch * 8] =
                *(const half8*)(Ahi + (size_t)(bm + row) * K + k0 + ch * 8);
            *(half8*)&sm.sB[row][ch * 8] =
                *(const half8*)(BT + (size_t)(bn + row) * K + k0 + ch * 8);
        }
        __syncthreads();
#pragma unroll
        for (int ks = 0; ks < 2; ++ks) {
            const int ko = ks * 32 + q * 8;
            half8 ah[2], bh[2];
#pragma unroll
            for (int tr = 0; tr < 2; ++tr)
                ah[tr] = *(const half8*)&sm.sA[32 * wr + 16 * tr + L15][ko];
#pragma unroll
            for (int tc = 0; tc < 2; ++tc)
                bh[tc] = *(const half8*)&sm.sB[32 * wc + 16 * tc + L15][ko];
#pragma unroll
            for (int tr = 0; tr < 2; ++tr)
#pragma unroll
                for (int tc = 0; tc < 2; ++tc)
                    acc[tr][tc] = __builtin_amdgcn_mfma_f32_16x16x32_f16(ah[tr], bh[tc], acc[tr][tc], 0, 0, 0);
        }
        __syncthreads();
    }
#pragma unroll
    for (int tr = 0; tr < 2; ++tr)
#pragma unroll
        for (int tc = 0; tc < 2; ++tc)
#pragma unroll
            for (int r = 0; r < 4; ++r) {
                int rowg = bm + 32 * wr + 16 * tr + q * 4 + r;
                int colg = bn + 32 * wc + 16 * tc + L15;
                Chi[(size_t)rowg * NHID + colg] = (_Float16)acc[tr][tc][r];
            }
}

// ---------------------------------------------------------------- dedup body (2 rows per call)
__device__ __forceinline__ void dedup_body(
    char* smraw, const int* __restrict__ nbr, const int* __restrict__ rowcnt,
    const int* __restrict__ deg, int* __restrict__ cols, float* __restrict__ wout,
    float* __restrict__ rsum, int grp) {
    SmemDedup& sm = *(SmemDedup*)smraw;
    const int t = threadIdx.x;
    const int half = t >> 7, st = t & 127;
    const int wid = st >> 6, lane = t & 63;
    const int r = grp * 2 + half;
    int n = rowcnt[r]; if (n > RCAP) n = RCAP;
    if (st < n) sm.lc[half][st] = nbr[r * RCAP + st];
    __syncthreads();
    float dr = 1.f / sqrtf((float)deg[r]);
    bool keep = false; float wv = 0.f;
    if (st < n) {
        int c = sm.lc[half][st];
        int mult = 0; bool first = true;
        for (int i = 0; i < n; ++i) {
            int ci = sm.lc[half][i];
            if (ci == c) { mult++; if (i < st) first = false; }
        }
        keep = first;
        if (first) wv = (float)mult * dr * (1.f / sqrtf((float)deg[c]));
    }
    sm.kp[half][st] = keep ? 1 : 0; sm.lw[half][st] = wv;
    float rv = wv;
#pragma unroll
    for (int d = 1; d < 64; d <<= 1) rv += __shfl_xor(rv, d, 64);
    unsigned long long b = __ballot(keep);
    int pre = __popcll(b & ((1ull << lane) - 1ull));
    int cw = __popcll(b);
    if (lane == 0) { sm.cw[half][wid] = cw; sm.rw[half][wid] = rv; }
    __syncthreads();
    int total = sm.cw[half][0] + sm.cw[half][1];
    if (st == 0) rsum[r] = sm.rw[half][0] + sm.rw[half][1];
    const int base = r * KCAP;
    if (total <= KCAP) {
        int off = (wid ? sm.cw[half][0] : 0) + pre;
        if (keep) { cols[base + off] = sm.lc[half][st]; wout[base + off] = wv; }
        for (int m = total + st; m < KCAP; m += 128) { cols[base + m] = r; wout[base + m] = 0.f; }
    } else if (st == 0) {
        for (int s = 0; s < KCAP; ++s) {
            int best = -1;
            for (int i = 0; i < n; ++i) {
                if (!sm.kp[half][i]) continue;
                if (best < 0 || sm.lw[half][i] > sm.lw[half][best] ||
                    (sm.lw[half][i] == sm.lw[half][best] && sm.lc[half][i] < sm.lc[half][best])) best = i;
            }
            cols[base + s] = sm.lc[half][best]; wout[base + s] = sm.lw[half][best]; sm.kp[half][best] = 0;
        }
    }
}

// ---------------------------------------------------------------- medoid core (s_cols/s_a/s_rsum pre-loaded)
__device__ __forceinline__ void medoid_core(
    SmemMedoid& sm, const _Float16* __restrict__ Xhi, const float* __restrict__ bias,
    float* __restrict__ OutF, _Float16* __restrict__ OutHi, int node, int writeH) {
    const int t = threadIdx.x;
    const int w = t >> 6, lane = t & 63;
    const int L15 = lane & 15, q = lane >> 4;
    const int wr = w >> 1, wc = w & 1;

    f32x4 acc[2][2];
#pragma unroll
    for (int a = 0; a < 2; ++a)
#pragma unroll
        for (int b = 0; b < 2; ++b) acc[a][b] = (f32x4){0.f, 0.f, 0.f, 0.f};

    const int ch = t & 15, rr = t >> 4;
    const _Float16* rbase[4];
#pragma unroll
    for (int i = 0; i < 4; ++i)
        rbase[i] = Xhi + ((size_t)sm.s_cols[i * 16 + rr] << 8) + ch * 8;

    // ---- phase-0 gather (dims 0..127)
    half8 g0[4];
#pragma unroll
    for (int i = 0; i < 4; ++i) g0[i] = *(const half8*)rbase[i];
#pragma unroll
    for (int i = 0; i < 4; ++i) *(half8*)&sm.sh[i * 16 + rr][ch * 8] = g0[i];
    __syncthreads();

    // ---- issue phase-1 gather NOW; ~L2 latency hides under phase-0 MFMA (T14)
    half8 g1[4];
#pragma unroll
    for (int i = 0; i < 4; ++i) g1[i] = *(const half8*)(rbase[i] + 128);

    // ---- phase-0 MFMA
#pragma unroll
    for (int ks = 0; ks < 4; ++ks) {
        const int ko = ks * 32 + q * 8;
        half8 ah[2], bh[2];
#pragma unroll
        for (int tr = 0; tr < 2; ++tr) ah[tr] = *(const half8*)&sm.sh[32 * wr + 16 * tr + L15][ko];
#pragma unroll
        for (int tc = 0; tc < 2; ++tc) bh[tc] = *(const half8*)&sm.sh[32 * wc + 16 * tc + L15][ko];
#pragma unroll
        for (int tr = 0; tr < 2; ++tr)
#pragma unroll
            for (int tc = 0; tc < 2; ++tc)
                acc[tr][tc] = __builtin_amdgcn_mfma_f32_16x16x32_f16(ah[tr], bh[tc], acc[tr][tc], 0, 0, 0);
    }
    __syncthreads();

    // ---- phase-1 write + MFMA
#pragma unroll
    for (int i = 0; i < 4; ++i) *(half8*)&sm.sh[i * 16 + rr][ch * 8] = g1[i];
    __syncthreads();
#pragma unroll
    for (int ks = 0; ks < 4; ++ks) {
        const int ko = ks * 32 + q * 8;
        half8 ah[2], bh[2];
#pragma unroll
        for (int tr = 0; tr < 2; ++tr) ah[tr] = *(const half8*)&sm.sh[32 * wr + 16 * tr + L15][ko];
#pragma unroll
        for (int tc = 0; tc < 2; ++tc) bh[tc] = *(const half8*)&sm.sh[32 * wc + 16 * tc + L15][ko];
#pragma unroll
        for (int tr = 0; tr < 2; ++tr)
#pragma unroll
            for (int tc = 0; tc < 2; ++tc)
                acc[tr][tc] = __builtin_amdgcn_mfma_f32_16x16x32_f16(ah[tr], bh[tc], acc[tr][tc], 0, 0, 0);
    }
    // sm.sh holds dims 128..255 for the epilogue

#pragma unroll
    for (int tr = 0; tr < 2; ++tr)
#pragma unroll
        for (int tc = 0; tc < 2; ++tc)
            if (32 * wr + 16 * tr == 32 * wc + 16 * tc) {
#pragma unroll
                for (int r = 0; r < 4; ++r)
                    if (L15 == q * 4 + r) sm.s_sq[32 * wr + 16 * tr + L15] = acc[tr][tc][r];
            }
    __syncthreads();

    f32x4 sq4[2], a4[2];
#pragma unroll
    for (int tr = 0; tr < 2; ++tr) {
        sq4[tr] = *(const f32x4*)&sm.s_sq[32 * wr + 16 * tr + 4 * q];
        a4[tr]  = *(const f32x4*)&sm.s_a [32 * wr + 16 * tr + 4 * q];
    }
#pragma unroll
    for (int tc = 0; tc < 2; ++tc) {
        const int colg = 32 * wc + 16 * tc + L15;
        const float sqc = sm.s_sq[colg];
        float pj = 0.f;
#pragma unroll
        for (int tr = 0; tr < 2; ++tr)
#pragma unroll
            for (int r = 0; r < 4; ++r) {
                float d2 = sq4[tr][r] + sqc - 2.f * acc[tr][tc][r];
                float dist = d2 > 0.f ? __builtin_amdgcn_sqrtf(d2) : 0.f;
                pj = fmaf(a4[tr][r], dist, pj);
            }
        pj += __shfl_xor(pj, 16, 64);
        pj += __shfl_xor(pj, 32, 64);
        if (q == 0) sm.s_cpart[wr][colg] = pj;
    }
    __syncthreads();

    if (w == 0) {
        int j = lane;
        float c = sm.s_cpart[0][j] + sm.s_cpart[1][j];
        float aj = sm.s_a[j];
        bool valid = aj > 0.f;
        float cv = valid ? c : 3.4e38f;
        float mn = cv;
#pragma unroll
        for (int d = 1; d < 64; d <<= 1) mn = fminf(mn, __shfl_xor(mn, d, 64));
        float e = valid ? __expf(mn - c) * aj : 0.f;
        float s = e;
#pragma unroll
        for (int d = 1; d < 64; d <<= 1) s += __shfl_xor(s, d, 64);
        sm.s_u[j] = e * (sm.s_rsum / s);
    }
    __syncthreads();

    const int oct = t & 31, jb = t >> 5;
    float accd[8] = {0.f, 0.f, 0.f, 0.f, 0.f, 0.f, 0.f, 0.f};
#pragma unroll
    for (int jj = 0; jj < 8; ++jj) {
        int j = jb * 8 + jj;
        float u = sm.s_u[j];
        half8 xv;
        if (oct < 16) xv = *(const half8*)(Xhi + ((size_t)sm.s_cols[j] << 8) + oct * 8);
        else          xv = *(const half8*)&sm.sh[j][(oct - 16) * 8];
#pragma unroll
        for (int e = 0; e < 8; ++e) accd[e] = fmaf(u, (float)xv[e], accd[e]);
    }
#pragma unroll
    for (int e = 0; e < 8; ++e) accd[e] += __shfl_xor(accd[e], 32, 64);
    __syncthreads();   // sh reads above must drain before writing aliased s_red
    if (lane < 32) {
#pragma unroll
        for (int e = 0; e < 8; ++e) sm.s_red[w][9 * oct + e] = accd[e];
    }
    __syncthreads();
    const int idx = 9 * (t >> 3) + (t & 7);
    float o = sm.s_red[0][idx] + sm.s_red[1][idx] + sm.s_red[2][idx] + sm.s_red[3][idx];
    float res = fmaxf(o + bias[t], 0.f);
    size_t oi = (size_t)node * NHID + t;
    if (writeH) OutHi[oi] = (_Float16)res;
    else        OutF[oi] = res;
}

// ================================================================ D1: prep (xh, w1T, w2T) ∥ edge scatter
#define PREPB 512
__global__ __launch_bounds__(256) void k_prep_scatter(
    const float* __restrict__ x, _Float16* __restrict__ xh,
    const float* __restrict__ W1, _Float16* __restrict__ w1T,
    const float* __restrict__ W2, _Float16* __restrict__ w2T,
    const void* edges, int* rowcnt, int* nbr, int* deg, int E) {
    const int t = threadIdx.x;
    if ((int)blockIdx.x < PREPB) {
        const int gid = blockIdx.x * 256 + t, nthr = PREPB * 256;
        for (int i = gid; i < NNODE * 512 / 4; i += nthr) {
            float4 v = ((const float4*)x)[i];
            half4 h;
            h[0] = (_Float16)v.x; h[1] = (_Float16)v.y;
            h[2] = (_Float16)v.z; h[3] = (_Float16)v.w;
            *(half4*)&xh[4 * (size_t)i] = h;
        }
        for (int i = gid; i < 512 * NHID; i += nthr) {
            int k = i >> 8, n = i & 255;
            w1T[(size_t)n * 512 + k] = (_Float16)W1[i];
        }
        for (int i = gid; i < NHID * NHID; i += nthr) {
            int k = i >> 8, n = i & 255;
            w2T[(size_t)n * 256 + k] = (_Float16)W2[i];
        }
    } else {
        __shared__ int sflag;
        if (t < 64) {   // per-block dtype probe (L2-hot)
            const long long* e = (const long long*)edges;
            long long v = e[t];
            unsigned long long bad = __ballot(v < 0 || v >= (long long)NNODE);
            if (t == 0) sflag = (bad == 0) ? 1 : 0;
        }
        __syncthreads();
        const int fl = sflag;
        int i = ((int)blockIdx.x - PREPB) * 256 + t;
        if (i >= E + NNODE) return;
        int r, c;
        if (i < E) {
            if (fl) {
                const long long* e = (const long long*)edges;
                r = (int)e[i]; c = (int)e[E + i];
            } else {
                const int* e = (const int*)edges;
                r = e[i]; c = e[E + i];
            }
        } else { r = i - E; c = r; }   // self loop
        int pos = atomicAdd(&rowcnt[r], 1);
        if (pos < RCAP) nbr[r * RCAP + pos] = c;
        atomicAdd(&deg[c], 1);
    }
}

// ================================================================ D2: gemm1 (blocks 0..511) ∥ dedup
__global__ __launch_bounds__(256) void k_gemm1_dedup(
    const _Float16* __restrict__ xh, const _Float16* __restrict__ w1T,
    _Float16* __restrict__ X1,
    const int* __restrict__ nbr, const int* __restrict__ rowcnt,
    const int* __restrict__ deg,
    int* __restrict__ cols, float* __restrict__ wA, float* __restrict__ rsum) {
    __shared__ __align__(16) char smem[sizeof(SmemGemm)];
    if ((int)blockIdx.x < 512) {
        int g = blockIdx.x;
        gemm_body(smem, xh, w1T, X1, 512, (g >> 2) * 64, (g & 3) * 64);
    } else {
        dedup_body(smem, nbr, rowcnt, deg, cols, wA, rsum, (int)blockIdx.x - 512);
    }
}

// ================================================================ D3/D5: medoid layers
__global__ __launch_bounds__(256, 8) void k_medoid(
    const _Float16* __restrict__ X, const float* __restrict__ bias,
    float* __restrict__ OutF, _Float16* __restrict__ OutHi,
    const int* __restrict__ cols, const float* __restrict__ wts,
    const float* __restrict__ rsum, int writeH) {
    __shared__ __align__(16) SmemMedoid sm;
    const int node = blockIdx.x, t = threadIdx.x;
    if (t < 64) { sm.s_cols[t] = cols[node * KCAP + t]; sm.s_a[t] = wts[node * KCAP + t]; }
    if (t == 0) sm.s_rsum = rsum[node];
    __syncthreads();
    medoid_core(sm, X, bias, OutF, OutHi, node, writeH);
}

// ================================================================ D4: gemm layer 2
__global__ __launch_bounds__(256) void k_gemm2(
    const _Float16* __restrict__ Hh, const _Float16* __restrict__ w2T,
    _Float16* __restrict__ X2) {
    __shared__ __align__(16) char smem[sizeof(SmemGemm)];
    gemm_body(smem, Hh, w2T, X2, 256, blockIdx.x * 64, blockIdx.y * 64);
}

// ================================================================ launch
extern "C" void kernel_launch(void* const* d_in, const int* in_sizes, int n_in,
                              void* d_out, int out_size, void* d_ws, size_t ws_size,
                              hipStream_t stream) {
    const float* x  = (const float*)d_in[0];
    const void*  ei = d_in[1];
    const float* W1 = (const float*)d_in[2];
    const float* b1 = (const float*)d_in[3];
    const float* W2 = (const float*)d_in[4];
    const float* b2 = (const float*)d_in[5];
    float* out = (float*)d_out;
    const int E = in_sizes[1] / 2;

    char* p = (char*)d_ws;
    auto alloc = [&](size_t bytes) { char* q = p; p += (bytes + 255) & ~(size_t)255; return q; };
    int*      cnt    = (int*)alloc((size_t)2 * NNODE * 4);   // deg | rowcnt (single memset)
    int*      deg    = cnt;
    int*      rowcnt = cnt + NNODE;
    int*      colsA  = (int*)alloc((size_t)NNODE * KCAP * 4);
    float*    wAr    = (float*)alloc((size_t)NNODE * KCAP * 4);
    float*    rsum   = (float*)alloc((size_t)NNODE * 4);
    _Float16* xh     = (_Float16*)alloc((size_t)NNODE * 512 * 2);
    _Float16* w1T    = (_Float16*)alloc((size_t)512 * NHID * 2);
    _Float16* w2T    = (_Float16*)alloc((size_t)NHID * NHID * 2);
    _Float16* X1     = (_Float16*)alloc((size_t)NNODE * NHID * 2);   // also X2
    _Float16* Hh     = (_Float16*)alloc((size_t)NNODE * NHID * 2);
    int*      nbr    = (int*)alloc((size_t)NNODE * RCAP * 4);

    const int nscat = (E + NNODE + 255) / 256;

    hipMemsetAsync(cnt, 0, (size_t)2 * NNODE * 4, stream);
    k_prep_scatter<<<PREPB + nscat, 256, 0, stream>>>(x, xh, W1, w1T, W2, w2T,
                                                      ei, rowcnt, nbr, deg, E);
    k_gemm1_dedup<<<512 + NNODE / 2, 256, 0, stream>>>(xh, w1T, X1, nbr, rowcnt, deg,
                                                       colsA, wAr, rsum);
    k_medoid<<<NNODE, 256, 0, stream>>>(X1, b1, nullptr, Hh, colsA, wAr, rsum, 1);
    k_gemm2<<<dim3(NNODE / 64, NHID / 64), 256, 0, stream>>>(Hh, w2T, X1);
    k_medoid<<<NNODE, 256, 0, stream>>>(X1, b2, out, nullptr, colsA, wAr, rsum, 0);
}